// Round 1
// 1699.728 us; speedup vs baseline: 1.0979x; 1.0979x over previous
//
#include <hip/hip_runtime.h>

// ComplexAttention B=16, S=D=1024 — split-fp16 MFMA pipeline.
// Precision: operands split f32 -> (hi,lo) fp16; products Ahi*Bhi + Ahi*Blo + Alo*Bhi
// accumulate in f32 via v_mfma_f32_32x32x16_f16 (dropped Alo*Blo ~ 2^-22 rel).
// SP (split-pair) tensor layout: [row][kc=k/8] -> 16B hi-unit, 16B lo-unit
// (row stride 4096 B for K=1024). MFMA frag = 8 consecutive k of one component = 1 unit.
//
// GEMM: 256x256 tile, 8 waves (2Mx4N), 512 thr, 128 KiB LDS as ring of 4 K16
// buffers (A 16K + B 16K each). Depth-3 prefetch with counted s_waitcnt vmcnt(12)
// (never 0 in steady state), raw s_barrier (no drain), setprio(1) around the
// 24-MFMA cluster. LDS slot swizzle: slot = unit ^ ((row>>1)&3) -> 4-way-min
// bank pattern on ds_read_b128; global source pre-swizzled, LDS dest linear
// (global_load_lds constraint).
//
// ws (408 MB): qr_sp 64MB | qi_sp | ki_sp | krT_sp | vrT_sp | viT_sp | Wsp 6x4MB
// d_out used as scratch: [0:64MB) Xsp then S(f32); [64:128MB) F0(f32) then attn_sp.
// out_r/out_i f32 overwrite qr_sp/qi_sp (dead after scores). LN: ws -> d_out.

#define MB 1048576L

typedef _Float16 h8 __attribute__((ext_vector_type(8)));
typedef _Float16 h4 __attribute__((ext_vector_type(4)));
typedef float f32x16 __attribute__((ext_vector_type(16)));

__device__ __forceinline__ float wave_sum(float x) {
#pragma unroll
  for (int o = 32; o; o >>= 1) x += __shfl_xor(x, o);
  return x;
}
__device__ __forceinline__ float wave_max(float x) {
#pragma unroll
  for (int o = 32; o; o >>= 1) x = fmaxf(x, __shfl_xor(x, o));
  return x;
}

__device__ __forceinline__ void async16(const char* g, char* l) {
  __builtin_amdgcn_global_load_lds(
      (const __attribute__((address_space(1))) unsigned int*)g,
      (__attribute__((address_space(3))) unsigned int*)l, 16, 0, 0);
}

// f32 x8 -> hi8/lo8 fp16
__device__ __forceinline__ void split8(const float* v, h8& hi, h8& lo) {
#pragma unroll
  for (int j = 0; j < 8; ++j) {
    _Float16 h = (_Float16)v[j];
    hi[j] = h;
    lo[j] = (_Float16)(v[j] - (float)h);
  }
}

// straight split: in f32[n8*8] -> out SP units (32B per 8 elems)
__global__ void split_pass(const float* __restrict__ in, char* __restrict__ out, long n8) {
  long i = (long)blockIdx.x * blockDim.x + threadIdx.x;
  if (i >= n8) return;
  float v[8];
  const float4* p = (const float4*)(in + i * 8);
  float4 a = p[0], b = p[1];
  v[0] = a.x; v[1] = a.y; v[2] = a.z; v[3] = a.w;
  v[4] = b.x; v[5] = b.y; v[6] = b.z; v[7] = b.w;
  h8 hi, lo;
  split8(v, hi, lo);
  *(h8*)(out + i * 32) = hi;
  *(h8*)(out + i * 32 + 16) = lo;
}

// Split-fp16 MFMA GEMM: C[256x256 tile] = scale * sum_pairs A_sp @ B_sp^T (+bias)
// A_sp: [M][K] k-contig SP; B_sp: [N][K] k-contig SP; K=1024 per pair.
// EPI 0: f32 store (opt bias, scale). EPI 1: split-pair TRANSPOSED store (bias):
//   Ct[b][n][k=row%1024] for projections (rows = b*1024+s).
template <int EPI>
__launch_bounds__(512, 2)
__global__ void gemm_sp(const char* __restrict__ A1, const char* __restrict__ B1,
                        const char* __restrict__ A2, const char* __restrict__ B2,
                        int npair, const float* __restrict__ bias,
                        float* __restrict__ Cf, char* __restrict__ Ct,
                        float scale, long zA, long zB, long zC) {
  // ring of 4 buffers; each: A [0,16K) + B [16K,32K); buffer q at q*32768
  __shared__ __align__(16) char lds[131072];
  const int tid = threadIdx.x;
  const int w = tid >> 6, lam = tid & 63;
  const int ln31 = lam & 31, half = lam >> 5;
  const int wr = w >> 2, wc = w & 3;  // wave tile: rows wr*128, cols wc*64
  const int bm0 = blockIdx.y * 256, bn0 = blockIdx.x * 256;
  const long z = blockIdx.z;

  const char* A1z = A1 + z * zA;
  const char* B1z = B1 + z * zB;
  const char* A2z = A2 ? A2 + z * zA : A1z;
  const char* B2z = B2 ? B2 + z * zB : B1z;

  // staging invariants: wave w stages rows [w*32, w*32+32) of A and B.
  // instr i covers 16 rows: local row = w*32 + i*16 + (lam>>2), slot = lam&3.
  // slot s at row r holds unit u = s ^ ((r>>1)&3)  ->  stU = (lam&3)^((lam>>3)&3)
  const int stRow = w * 32 + (lam >> 2);
  const int stU = (lam & 3) ^ ((lam >> 3) & 3);
  const long sAo = (long)(bm0 + stRow) * 4096 + stU * 16;
  const long sBo = (long)(bn0 + stRow) * 4096 + stU * 16;

  // read invariants: row r -> (r>>1)&3 == (ln31>>1)&3 (bases are mult of 32)
  const int e2 = (ln31 >> 1) & 3;
  const int offH = ((2 * half) ^ e2) * 16;
  const int offL = ((2 * half + 1) ^ e2) * 16;
  const int rA = (wr * 128 + ln31) * 64;          // + mt*2048
  const int rB = 16384 + (wc * 64 + ln31) * 64;   // + nt*2048

  const int Nk = npair * 64;  // K16 steps
  f32x16 acc[4][2] = {};

  auto STAGE = [&](int tt) {
    const long ko = (long)(tt & 63) * 64;
    char* d = lds + (tt & 3) * 32768 + w * 2048;
    const char* As = ((tt >> 6) ? A2z : A1z) + sAo + ko;
    const char* Bs = ((tt >> 6) ? B2z : B1z) + sBo + ko;
    async16(As, d);
    async16(As + 65536, d + 1024);       // i=1: +16 rows
    async16(Bs, d + 16384);
    async16(Bs + 65536, d + 17408);
  };

  STAGE(0);
  STAGE(1);
  STAGE(2);
  __builtin_amdgcn_sched_barrier(0);

  for (int t = 0; t < Nk; ++t) {
    const int left = Nk - t;
    if (left > 3) STAGE(t + 3);
    __builtin_amdgcn_sched_barrier(0);
    // counted wait: oldest 4 loads (this t's buffer) complete; 12 stay in flight
    if (left > 3)
      asm volatile("s_waitcnt vmcnt(12)" ::: "memory");
    else if (left == 3)
      asm volatile("s_waitcnt vmcnt(8)" ::: "memory");
    else if (left == 2)
      asm volatile("s_waitcnt vmcnt(4)" ::: "memory");
    else
      asm volatile("s_waitcnt vmcnt(0)" ::: "memory");
    __builtin_amdgcn_s_barrier();        // buffer t&3 ready for all waves
    __builtin_amdgcn_sched_barrier(0);

    const char* bq = lds + (t & 3) * 32768;
    h8 bh[2], bl[2], ah[4], al[4];
#pragma unroll
    for (int nt = 0; nt < 2; ++nt) {
      bh[nt] = *(const h8*)(bq + rB + nt * 2048 + offH);
      bl[nt] = *(const h8*)(bq + rB + nt * 2048 + offL);
    }
#pragma unroll
    for (int mt = 0; mt < 4; ++mt) {
      ah[mt] = *(const h8*)(bq + rA + mt * 2048 + offH);
      al[mt] = *(const h8*)(bq + rA + mt * 2048 + offL);
    }
    __builtin_amdgcn_s_setprio(1);
#pragma unroll
    for (int mt = 0; mt < 4; ++mt)
#pragma unroll
      for (int nt = 0; nt < 2; ++nt) {
        acc[mt][nt] = __builtin_amdgcn_mfma_f32_32x32x16_f16(ah[mt], bh[nt], acc[mt][nt], 0, 0, 0);
        acc[mt][nt] = __builtin_amdgcn_mfma_f32_32x32x16_f16(ah[mt], bl[nt], acc[mt][nt], 0, 0, 0);
        acc[mt][nt] = __builtin_amdgcn_mfma_f32_32x32x16_f16(al[mt], bh[nt], acc[mt][nt], 0, 0, 0);
      }
    __builtin_amdgcn_s_setprio(0);
    __builtin_amdgcn_sched_barrier(0);
    __builtin_amdgcn_s_barrier();        // all reads done -> buffer reusable
  }

  const int wm = wr * 128, wn = wc * 64;
  if (EPI == 0) {
    float* C = Cf + z * zC;
#pragma unroll
    for (int nt = 0; nt < 2; ++nt) {
      const int col = bn0 + wn + nt * 32 + ln31;
      const float bv = bias ? bias[col] : 0.0f;
#pragma unroll
      for (int mt = 0; mt < 4; ++mt) {
#pragma unroll
        for (int q = 0; q < 4; ++q) {
#pragma unroll
          for (int i = 0; i < 4; ++i) {
            const int row = bm0 + wm + mt * 32 + q * 8 + half * 4 + i;
            C[(long)row * 1024 + col] = acc[mt][nt][q * 4 + i] * scale + bv;
          }
        }
      }
    }
  } else {
    // transposed split store: rows (b,s) -> Ct[b][col][s]
    const long b = bm0 >> 10;
    char* Tb = Ct + b * (4 * MB);
    const int sbase = bm0 & 1023;
#pragma unroll
    for (int nt = 0; nt < 2; ++nt) {
      const int n = bn0 + wn + nt * 32 + ln31;
      const float bv = bias ? bias[n] : 0.0f;
#pragma unroll
      for (int mt = 0; mt < 4; ++mt) {
#pragma unroll
        for (int q = 0; q < 4; ++q) {
          const int sl = sbase + wm + mt * 32 + q * 8 + half * 4;
          h4 hv, lv;
#pragma unroll
          for (int i = 0; i < 4; ++i) {
            float y = acc[mt][nt][q * 4 + i] * scale + bv;
            _Float16 h = (_Float16)y;
            hv[i] = h;
            lv[i] = (_Float16)(y - (float)h);
          }
          char* dst = Tb + (long)n * 4096 + (sl >> 3) * 32 + (sl & 7) * 2;
          *(h4*)dst = hv;
          *(h4*)(dst + 16) = lv;
        }
      }
    }
  }
}

// softmax over 1024 per row, writes split-pair fp16 attn. 128 threads/row.
__launch_bounds__(128)
__global__ void softmax_split(const float* __restrict__ S, char* __restrict__ attn) {
  const long row = blockIdx.x;
  const int t = threadIdx.x;
  const float* p = S + row * 1024 + t * 8;
  float4 a = *(const float4*)p, b = *(const float4*)(p + 4);
  float v[8] = {a.x, a.y, a.z, a.w, b.x, b.y, b.z, b.w};
  float m = v[0];
#pragma unroll
  for (int j = 1; j < 8; ++j) m = fmaxf(m, v[j]);
  m = wave_max(m);
  __shared__ float redm[2], reds[2];
  const int wave = t >> 6, lane = t & 63;
  if (lane == 0) redm[wave] = m;
  __syncthreads();
  m = fmaxf(redm[0], redm[1]);
  float s = 0.f;
#pragma unroll
  for (int j = 0; j < 8; ++j) {
    v[j] = __expf(v[j] - m);
    s += v[j];
  }
  s = wave_sum(s);
  if (lane == 0) reds[wave] = s;
  __syncthreads();
  const float inv = 1.0f / (reds[0] + reds[1]);
#pragma unroll
  for (int j = 0; j < 8; ++j) v[j] *= inv;
  h8 hi, lo;
  split8(v, hi, lo);
  char* dst = attn + row * 4096 + t * 32;
  *(h8*)dst = hi;
  *(h8*)(dst + 16) = lo;
}

// complex layernorm rows of 1024: z = inr + i*ini -> d_out (real | imag halves)
__launch_bounds__(256)
__global__ void complex_ln(const float* __restrict__ inr, const float* __restrict__ ini,
                           float* __restrict__ outr, float* __restrict__ outi,
                           const float* __restrict__ a2, const float* __restrict__ b2) {
  const long row = blockIdx.x;
  const int tid = threadIdx.x;
  const float* xr = inr + row * 1024;
  const float* xi = ini + row * 1024;
  float4 r4 = *(const float4*)(xr + tid * 4);
  float4 i4 = *(const float4*)(xi + tid * 4);
  float sx = r4.x + r4.y + r4.z + r4.w;
  float sy = i4.x + i4.y + i4.z + i4.w;
  float sxx = r4.x * r4.x + r4.y * r4.y + r4.z * r4.z + r4.w * r4.w;
  float syy = i4.x * i4.x + i4.y * i4.y + i4.z * i4.z + i4.w * i4.w;
  float sxy = r4.x * i4.x + r4.y * i4.y + r4.z * i4.z + r4.w * i4.w;
  sx = wave_sum(sx); sy = wave_sum(sy);
  sxx = wave_sum(sxx); syy = wave_sum(syy); sxy = wave_sum(sxy);
  __shared__ float red[4][5];
  const int wave = tid >> 6, lane = tid & 63;
  if (lane == 0) {
    red[wave][0] = sx; red[wave][1] = sy; red[wave][2] = sxx;
    red[wave][3] = syy; red[wave][4] = sxy;
  }
  __syncthreads();
  sx = red[0][0] + red[1][0] + red[2][0] + red[3][0];
  sy = red[0][1] + red[1][1] + red[2][1] + red[3][1];
  sxx = red[0][2] + red[1][2] + red[2][2] + red[3][2];
  syy = red[0][3] + red[1][3] + red[2][3] + red[3][3];
  sxy = red[0][4] + red[1][4] + red[2][4] + red[3][4];
  const float invN = 1.0f / 1024.0f;
  const float mx = sx * invN, my = sy * invN;
  const float vx = (sxx * invN - mx * mx) - (syy * invN - my * my);
  const float vy = 2.0f * (sxy * invN - mx * my);
  const float wx = vx + 1e-6f, wy = vy;
  const float rm = sqrtf(wx * wx + wy * wy);
  const float sre = sqrtf(fmaxf(rm + wx, 0.0f) * 0.5f);
  const float sim = copysignf(sqrtf(fmaxf(rm - wx, 0.0f) * 0.5f), wy);
  const float ir = 1.0f / fmaxf(rm, 1e-30f);
  float4 a4 = *(const float4*)(a2 + tid * 4);
  float4 b4 = *(const float4*)(b2 + tid * 4);
  float4 orr, oii;
  {
    float zx = r4.x - mx, zy = i4.x - my;
    orr.x = a4.x * ((zx * sre + zy * sim) * ir) + b4.x;
    oii.x = a4.x * ((zy * sre - zx * sim) * ir);
  }
  {
    float zx = r4.y - mx, zy = i4.y - my;
    orr.y = a4.y * ((zx * sre + zy * sim) * ir) + b4.y;
    oii.y = a4.y * ((zy * sre - zx * sim) * ir);
  }
  {
    float zx = r4.z - mx, zy = i4.z - my;
    orr.z = a4.z * ((zx * sre + zy * sim) * ir) + b4.z;
    oii.z = a4.z * ((zy * sre - zx * sim) * ir);
  }
  {
    float zx = r4.w - mx, zy = i4.w - my;
    orr.w = a4.w * ((zx * sre + zy * sim) * ir) + b4.w;
    oii.w = a4.w * ((zy * sre - zx * sim) * ir);
  }
  *(float4*)(outr + row * 1024 + tid * 4) = orr;
  *(float4*)(outi + row * 1024 + tid * 4) = oii;
}

extern "C" void kernel_launch(void* const* d_in, const int* in_sizes, int n_in,
                              void* d_out, int out_size, void* d_ws, size_t ws_size,
                              hipStream_t stream) {
  const float* X[6];
  for (int i = 0; i < 6; ++i) X[i] = (const float*)d_in[i];
  const float* W[6];
  const float* bia[6];
  for (int i = 0; i < 6; ++i) {
    W[i] = (const float*)d_in[6 + 2 * i];
    bia[i] = (const float*)d_in[7 + 2 * i];
  }
  const float* a2 = (const float*)d_in[18];
  const float* b2 = (const float*)d_in[19];

  char* ws = (char*)d_ws;
  char* qr = ws;
  char* qi = ws + 64 * MB;
  char* ki = ws + 128 * MB;
  char* krT = ws + 192 * MB;
  char* vrT = ws + 256 * MB;
  char* viT = ws + 320 * MB;
  char* Wsp[6];
  for (int i = 0; i < 6; ++i) Wsp[i] = ws + 384 * MB + (long)i * 4 * MB;

  char* dob = (char*)d_out;
  char* Xsp = dob;                       // [0, 64MB)
  float* F0 = (float*)(dob + 64 * MB);   // [64, 128MB)
  float* Sf = (float*)dob;               // scores f32 (after Xsp dead)
  char* attn = dob + 64 * MB;            // attn split (after F0 dead)
  float* outr = (float*)ws;              // over qr_sp
  float* outi = (float*)(ws + 64 * MB);  // over qi_sp

  dim3 blk(256), gblk(512);
  dim3 proj_g(4, 64, 1), bat_g(4, 4, 16);

  // W splits
  for (int i = 0; i < 6; ++i)
    split_pass<<<dim3(512), blk, 0, stream>>>(W[i], Wsp[i], 131072L);

  // qr = q_real @ Wq_r^T + b  (f32 -> F0 -> split)
  split_pass<<<dim3(8192), blk, 0, stream>>>(X[0], Xsp, 2097152L);
  gemm_sp<0><<<proj_g, gblk, 0, stream>>>(Xsp, Wsp[0], nullptr, nullptr, 1, bia[0], F0, nullptr, 1.0f, 0, 0, 0);
  split_pass<<<dim3(8192), blk, 0, stream>>>(F0, qr, 2097152L);
  // qi
  split_pass<<<dim3(8192), blk, 0, stream>>>(X[1], Xsp, 2097152L);
  gemm_sp<0><<<proj_g, gblk, 0, stream>>>(Xsp, Wsp[1], nullptr, nullptr, 1, bia[1], F0, nullptr, 1.0f, 0, 0, 0);
  split_pass<<<dim3(8192), blk, 0, stream>>>(F0, qi, 2097152L);
  // ki
  split_pass<<<dim3(8192), blk, 0, stream>>>(X[3], Xsp, 2097152L);
  gemm_sp<0><<<proj_g, gblk, 0, stream>>>(Xsp, Wsp[3], nullptr, nullptr, 1, bia[3], F0, nullptr, 1.0f, 0, 0, 0);
  split_pass<<<dim3(8192), blk, 0, stream>>>(F0, ki, 2097152L);
  // krT (transposed split epilogue)
  split_pass<<<dim3(8192), blk, 0, stream>>>(X[2], Xsp, 2097152L);
  gemm_sp<1><<<proj_g, gblk, 0, stream>>>(Xsp, Wsp[2], nullptr, nullptr, 1, bia[2], nullptr, krT, 1.0f, 0, 0, 0);
  // vrT
  split_pass<<<dim3(8192), blk, 0, stream>>>(X[4], Xsp, 2097152L);
  gemm_sp<1><<<proj_g, gblk, 0, stream>>>(Xsp, Wsp[4], nullptr, nullptr, 1, bia[4], nullptr, vrT, 1.0f, 0, 0, 0);
  // viT
  split_pass<<<dim3(8192), blk, 0, stream>>>(X[5], Xsp, 2097152L);
  gemm_sp<1><<<proj_g, gblk, 0, stream>>>(Xsp, Wsp[5], nullptr, nullptr, 1, bia[5], nullptr, viT, 1.0f, 0, 0, 0);

  // scores = 0.125*(qr @ krT^T + qi @ ki^T), fused K=2048
  gemm_sp<0><<<bat_g, gblk, 0, stream>>>(qr, krT, qi, ki, 2, nullptr, Sf, nullptr, 0.125f,
                                         4 * MB, 4 * MB, 1048576L);
  // softmax + split
  softmax_split<<<dim3(16384), dim3(128), 0, stream>>>(Sf, attn);
  // out = attn @ v
  gemm_sp<0><<<bat_g, gblk, 0, stream>>>(attn, vrT, nullptr, nullptr, 1, nullptr, outr, nullptr, 1.0f,
                                         4 * MB, 4 * MB, 1048576L);
  gemm_sp<0><<<bat_g, gblk, 0, stream>>>(attn, viT, nullptr, nullptr, 1, nullptr, outi, nullptr, 1.0f,
                                         4 * MB, 4 * MB, 1048576L);
  // complex layernorm ws -> d_out
  complex_ln<<<dim3(16384), blk, 0, stream>>>(outr, outi, (float*)d_out,
                                              (float*)(dob + 64 * MB), a2, b2);
}

// Round 2
// 1632.932 us; speedup vs baseline: 1.1428x; 1.0409x over previous
//
#include <hip/hip_runtime.h>

// ComplexAttention B=16, S=D=1024 — split-fp16 MFMA pipeline.
// Precision: operands split f32 -> (hi,lo) fp16; products Ahi*Bhi + Ahi*Blo + Alo*Bhi
// accumulate in f32 via v_mfma_f32_32x32x16_f16 (dropped Alo*Blo ~ 2^-22 rel).
// SP (split-pair) tensor layout: [row][kc=k/8] -> 16B hi-unit, 16B lo-unit
// (row stride 4096 B for K=1024). MFMA frag = 8 consecutive k of one component = 1 unit.
//
// GEMM: 256x256 tile, 8 waves (2Mx4N), 512 thr, 128 KiB LDS as ring of 4 K16
// buffers. REGISTER double-buffered fragments: at step t the wave ds_reads
// step t+1's frags into the alternate reg set, then MFMAs step t's set ->
// LDS service overlaps the 1536-cyc MFMA issue window (break the strict
// LDS-phase/MFMA-phase alternation measured at 3900 cyc/step in R1).
// One barrier per step. vmcnt(4) = 2 stages in flight; STAGE(t+3) issued
// after the barrier (WAR-safe: all waves' reads of buf (t-1)&3 retired).
//
// EPI 0: f32 C. EPI 1: transposed SP store. EPI 2 (new): direct row-major SP
// via wave-local LDS transpose ([32][65] f32 pad) — removes F0 + split_pass.
//
// ws (408 MB): qr_sp 64MB | qi_sp | ki_sp | krT_sp | vrT_sp | viT_sp | Wsp 6x4MB
// d_out used as scratch: [0:64MB) Xsp then S(f32); [64:128MB) attn_sp.
// out_r/out_i f32 overwrite qr_sp/qi_sp (dead after scores). LN: ws -> d_out.

#define MB 1048576L

typedef _Float16 h8 __attribute__((ext_vector_type(8)));
typedef _Float16 h4 __attribute__((ext_vector_type(4)));
typedef float f32x16 __attribute__((ext_vector_type(16)));

__device__ __forceinline__ float wave_sum(float x) {
#pragma unroll
  for (int o = 32; o; o >>= 1) x += __shfl_xor(x, o);
  return x;
}
__device__ __forceinline__ float wave_max(float x) {
#pragma unroll
  for (int o = 32; o; o >>= 1) x = fmaxf(x, __shfl_xor(x, o));
  return x;
}

__device__ __forceinline__ void async16(const char* g, char* l) {
  __builtin_amdgcn_global_load_lds(
      (const __attribute__((address_space(1))) unsigned int*)g,
      (__attribute__((address_space(3))) unsigned int*)l, 16, 0, 0);
}

// f32 x8 -> hi8/lo8 fp16
__device__ __forceinline__ void split8(const float* v, h8& hi, h8& lo) {
#pragma unroll
  for (int j = 0; j < 8; ++j) {
    _Float16 h = (_Float16)v[j];
    hi[j] = h;
    lo[j] = (_Float16)(v[j] - (float)h);
  }
}

// straight split: in f32[n8*8] -> out SP units (32B per 8 elems)
__global__ void split_pass(const float* __restrict__ in, char* __restrict__ out, long n8) {
  long i = (long)blockIdx.x * blockDim.x + threadIdx.x;
  if (i >= n8) return;
  float v[8];
  const float4* p = (const float4*)(in + i * 8);
  float4 a = p[0], b = p[1];
  v[0] = a.x; v[1] = a.y; v[2] = a.z; v[3] = a.w;
  v[4] = b.x; v[5] = b.y; v[6] = b.z; v[7] = b.w;
  h8 hi, lo;
  split8(v, hi, lo);
  *(h8*)(out + i * 32) = hi;
  *(h8*)(out + i * 32 + 16) = lo;
}

// Split-fp16 MFMA GEMM: C[256x256 tile] = scale * sum_pairs A_sp @ B_sp^T (+bias)
// A_sp: [M][K] k-contig SP; B_sp: [N][K] k-contig SP; K=1024 per pair.
template <int EPI>
__launch_bounds__(512, 2)
__global__ void gemm_sp(const char* __restrict__ A1, const char* __restrict__ B1,
                        const char* __restrict__ A2, const char* __restrict__ B2,
                        int npair, const float* __restrict__ bias,
                        float* __restrict__ Cf, char* __restrict__ Ct,
                        float scale, long zA, long zB, long zC) {
  // ring of 4 buffers; each: A [0,16K) + B [16K,32K); buffer q at q*32768
  __shared__ __align__(16) char lds[131072];
  const int tid = threadIdx.x;
  const int w = tid >> 6, lam = tid & 63;
  const int ln31 = lam & 31, half = lam >> 5;
  const int wr = w >> 2, wc = w & 3;  // wave tile: rows wr*128, cols wc*64
  const int bm0 = blockIdx.y * 256, bn0 = blockIdx.x * 256;
  const long z = blockIdx.z;

  const char* A1z = A1 + z * zA;
  const char* B1z = B1 + z * zB;
  const char* A2z = A2 ? A2 + z * zA : A1z;
  const char* B2z = B2 ? B2 + z * zB : B1z;

  // staging: wave w stages rows [w*32, w*32+32) of A and B; 2 instrs x 16 rows.
  // slot s at row r holds unit u = s ^ ((r>>1)&3)
  const int stRow = w * 32 + (lam >> 2);
  const int stU = (lam & 3) ^ ((lam >> 3) & 3);
  const long sAo = (long)(bm0 + stRow) * 4096 + stU * 16;
  const long sBo = (long)(bn0 + stRow) * 4096 + stU * 16;

  // read invariants: row r -> (r>>1)&3 == (ln31>>1)&3 (bases are mult of 32)
  const int e2 = (ln31 >> 1) & 3;
  const int offH = ((2 * half) ^ e2) * 16;
  const int offL = ((2 * half + 1) ^ e2) * 16;
  const int rA = (wr * 128 + ln31) * 64;          // + mt*2048
  const int rB = 16384 + (wc * 64 + ln31) * 64;   // + nt*2048

  const int Nk = npair * 64;  // K16 steps
  f32x16 acc[4][2] = {};

  auto STAGE = [&](int tt) {
    const long ko = (long)(tt & 63) * 64;
    char* d = lds + (tt & 3) * 32768 + w * 2048;
    const char* As = ((tt >> 6) ? A2z : A1z) + sAo + ko;
    const char* Bs = ((tt >> 6) ? B2z : B1z) + sBo + ko;
    async16(As, d);
    async16(As + 65536, d + 1024);       // +16 rows
    async16(Bs, d + 16384);
    async16(Bs + 65536, d + 17408);
  };

  h8 ahA[4], alA[4], bhA[2], blA[2];
  h8 ahB[4], alB[4], bhB[2], blB[2];

  auto READF = [&](int tt, h8* ah, h8* al, h8* bh, h8* bl) {
    const char* bq = lds + (tt & 3) * 32768;
#pragma unroll
    for (int nt = 0; nt < 2; ++nt) {
      bh[nt] = *(const h8*)(bq + rB + nt * 2048 + offH);
      bl[nt] = *(const h8*)(bq + rB + nt * 2048 + offL);
    }
#pragma unroll
    for (int mt = 0; mt < 4; ++mt) {
      ah[mt] = *(const h8*)(bq + rA + mt * 2048 + offH);
      al[mt] = *(const h8*)(bq + rA + mt * 2048 + offL);
    }
  };

  auto MFMAS = [&](const h8* ah, const h8* al, const h8* bh, const h8* bl) {
    __builtin_amdgcn_s_setprio(1);
#pragma unroll
    for (int mt = 0; mt < 4; ++mt)
#pragma unroll
      for (int nt = 0; nt < 2; ++nt) {
        acc[mt][nt] = __builtin_amdgcn_mfma_f32_32x32x16_f16(ah[mt], bh[nt], acc[mt][nt], 0, 0, 0);
        acc[mt][nt] = __builtin_amdgcn_mfma_f32_32x32x16_f16(ah[mt], bl[nt], acc[mt][nt], 0, 0, 0);
        acc[mt][nt] = __builtin_amdgcn_mfma_f32_32x32x16_f16(al[mt], bh[nt], acc[mt][nt], 0, 0, 0);
      }
    __builtin_amdgcn_s_setprio(0);
  };

  // prologue: 3 stages in flight, buf0 ready, frags(0) -> set A
  STAGE(0);
  STAGE(1);
  STAGE(2);
  asm volatile("s_waitcnt vmcnt(8)" ::: "memory");
  __builtin_amdgcn_s_barrier();
  __builtin_amdgcn_sched_barrier(0);
  READF(0, ahA, alA, bhA, blA);

  for (int t = 0; t < Nk; t += 2) {
    // even step: MFMA set A, load set B (frags t+1 from buf (t+1)&3)
    if (t < Nk - 2)
      asm volatile("s_waitcnt vmcnt(4)" ::: "memory");
    else
      asm volatile("s_waitcnt vmcnt(0)" ::: "memory");
    __builtin_amdgcn_s_barrier();
    __builtin_amdgcn_sched_barrier(0);
    if (t + 3 < Nk) STAGE(t + 3);
    READF(t + 1, ahB, alB, bhB, blB);
    __builtin_amdgcn_sched_barrier(0);
    MFMAS(ahA, alA, bhA, blA);
    __builtin_amdgcn_sched_barrier(0);

    // odd step: MFMA set B, load set A (frags t+2)
    const int t1 = t + 1;
    if (t1 < Nk - 1) {
      if (t1 < Nk - 2)
        asm volatile("s_waitcnt vmcnt(4)" ::: "memory");
      else
        asm volatile("s_waitcnt vmcnt(0)" ::: "memory");
      __builtin_amdgcn_s_barrier();
      __builtin_amdgcn_sched_barrier(0);
      if (t1 + 3 < Nk) STAGE(t1 + 3);
      READF(t1 + 1, ahA, alA, bhA, blA);
    }
    __builtin_amdgcn_sched_barrier(0);
    MFMAS(ahB, alB, bhB, blB);
    __builtin_amdgcn_sched_barrier(0);
  }

  const int wm = wr * 128, wn = wc * 64;
  if (EPI == 0) {
    float* C = Cf + z * zC;
#pragma unroll
    for (int nt = 0; nt < 2; ++nt) {
      const int col = bn0 + wn + nt * 32 + ln31;
      const float bv = bias ? bias[col] : 0.0f;
#pragma unroll
      for (int mt = 0; mt < 4; ++mt) {
#pragma unroll
        for (int q = 0; q < 4; ++q) {
#pragma unroll
          for (int i = 0; i < 4; ++i) {
            const int row = bm0 + wm + mt * 32 + q * 8 + half * 4 + i;
            C[(long)row * 1024 + col] = acc[mt][nt][q * 4 + i] * scale + bv;
          }
        }
      }
    }
  } else if (EPI == 1) {
    // transposed split store: rows (b,s) -> Ct[b][col][s]
    const long b = bm0 >> 10;
    char* Tb = Ct + b * (4 * MB);
    const int sbase = bm0 & 1023;
#pragma unroll
    for (int nt = 0; nt < 2; ++nt) {
      const int n = bn0 + wn + nt * 32 + ln31;
      const float bv = bias ? bias[n] : 0.0f;
#pragma unroll
      for (int mt = 0; mt < 4; ++mt) {
#pragma unroll
        for (int q = 0; q < 4; ++q) {
          const int sl = sbase + wm + mt * 32 + q * 8 + half * 4;
          h4 hv, lv;
#pragma unroll
          for (int i = 0; i < 4; ++i) {
            float y = acc[mt][nt][q * 4 + i] * scale + bv;
            _Float16 h = (_Float16)y;
            hv[i] = h;
            lv[i] = (_Float16)(y - (float)h);
          }
          char* dst = Tb + (long)n * 4096 + (sl >> 3) * 32 + (sl & 7) * 2;
          *(h4*)dst = hv;
          *(h4*)(dst + 16) = lv;
        }
      }
    }
  } else {
    // EPI 2: direct row-major SP store via wave-local LDS transpose.
    // All ring reads retired before each wave's final MFMA issue; one full
    // sync then each wave owns lds + w*8320 ([32][65] f32, pad kills conflicts).
    __syncthreads();
    float* T = (float*)(lds + w * 8320);
    const long gr0 = bm0 + wm;
    const int u0 = (bn0 + wn) >> 3;  // global unit base (8 units per wave)
    float bvv[2];
#pragma unroll
    for (int nt = 0; nt < 2; ++nt)
      bvv[nt] = bias ? bias[bn0 + wn + nt * 32 + ln31] : 0.0f;
    const int r = lam & 31;
    const int uh = lam >> 5;
#pragma unroll
    for (int mt = 0; mt < 4; ++mt) {
      // scatter: acc rows -> T[row][col]
#pragma unroll
      for (int nt = 0; nt < 2; ++nt) {
        const int col = nt * 32 + ln31;
#pragma unroll
        for (int q = 0; q < 4; ++q) {
#pragma unroll
          for (int i = 0; i < 4; ++i)
            T[(q * 8 + half * 4 + i) * 65 + col] = acc[mt][nt][q * 4 + i] * scale + bvv[nt];
        }
      }
      // gather k-contig, split, store 32B SP chunks
#pragma unroll
      for (int u4 = 0; u4 < 4; ++u4) {
        const int u = uh * 4 + u4;
        const float* src = T + r * 65 + u * 8;
        float vv[8];
#pragma unroll
        for (int j = 0; j < 8; ++j) vv[j] = src[j];
        h8 hi, lo;
        split8(vv, hi, lo);
        char* dst = Ct + (gr0 + mt * 32 + r) * 4096L + (long)(u0 + u) * 32;
        *(h8*)dst = hi;
        *(h8*)(dst + 16) = lo;
      }
    }
  }
}

// softmax over 1024 per row, writes split-pair fp16 attn. 128 threads/row.
__launch_bounds__(128)
__global__ void softmax_split(const float* __restrict__ S, char* __restrict__ attn) {
  const long row = blockIdx.x;
  const int t = threadIdx.x;
  const float* p = S + row * 1024 + t * 8;
  float4 a = *(const float4*)p, b = *(const float4*)(p + 4);
  float v[8] = {a.x, a.y, a.z, a.w, b.x, b.y, b.z, b.w};
  float m = v[0];
#pragma unroll
  for (int j = 1; j < 8; ++j) m = fmaxf(m, v[j]);
  m = wave_max(m);
  __shared__ float redm[2], reds[2];
  const int wave = t >> 6, lane = t & 63;
  if (lane == 0) redm[wave] = m;
  __syncthreads();
  m = fmaxf(redm[0], redm[1]);
  float s = 0.f;
#pragma unroll
  for (int j = 0; j < 8; ++j) {
    v[j] = __expf(v[j] - m);
    s += v[j];
  }
  s = wave_sum(s);
  if (lane == 0) reds[wave] = s;
  __syncthreads();
  const float inv = 1.0f / (reds[0] + reds[1]);
#pragma unroll
  for (int j = 0; j < 8; ++j) v[j] *= inv;
  h8 hi, lo;
  split8(v, hi, lo);
  char* dst = attn + row * 4096 + t * 32;
  *(h8*)dst = hi;
  *(h8*)(dst + 16) = lo;
}

// complex layernorm rows of 1024: z = inr + i*ini -> d_out (real | imag halves)
__launch_bounds__(256)
__global__ void complex_ln(const float* __restrict__ inr, const float* __restrict__ ini,
                           float* __restrict__ outr, float* __restrict__ outi,
                           const float* __restrict__ a2, const float* __restrict__ b2) {
  const long row = blockIdx.x;
  const int tid = threadIdx.x;
  const float* xr = inr + row * 1024;
  const float* xi = ini + row * 1024;
  float4 r4 = *(const float4*)(xr + tid * 4);
  float4 i4 = *(const float4*)(xi + tid * 4);
  float sx = r4.x + r4.y + r4.z + r4.w;
  float sy = i4.x + i4.y + i4.z + i4.w;
  float sxx = r4.x * r4.x + r4.y * r4.y + r4.z * r4.z + r4.w * r4.w;
  float syy = i4.x * i4.x + i4.y * i4.y + i4.z * i4.z + i4.w * i4.w;
  float sxy = r4.x * i4.x + r4.y * i4.y + r4.z * i4.z + r4.w * i4.w;
  sx = wave_sum(sx); sy = wave_sum(sy);
  sxx = wave_sum(sxx); syy = wave_sum(syy); sxy = wave_sum(sxy);
  __shared__ float red[4][5];
  const int wave = tid >> 6, lane = tid & 63;
  if (lane == 0) {
    red[wave][0] = sx; red[wave][1] = sy; red[wave][2] = sxx;
    red[wave][3] = syy; red[wave][4] = sxy;
  }
  __syncthreads();
  sx = red[0][0] + red[1][0] + red[2][0] + red[3][0];
  sy = red[0][1] + red[1][1] + red[2][1] + red[3][1];
  sxx = red[0][2] + red[1][2] + red[2][2] + red[3][2];
  syy = red[0][3] + red[1][3] + red[2][3] + red[3][3];
  sxy = red[0][4] + red[1][4] + red[2][4] + red[3][4];
  const float invN = 1.0f / 1024.0f;
  const float mx = sx * invN, my = sy * invN;
  const float vx = (sxx * invN - mx * mx) - (syy * invN - my * my);
  const float vy = 2.0f * (sxy * invN - mx * my);
  const float wx = vx + 1e-6f, wy = vy;
  const float rm = sqrtf(wx * wx + wy * wy);
  const float sre = sqrtf(fmaxf(rm + wx, 0.0f) * 0.5f);
  const float sim = copysignf(sqrtf(fmaxf(rm - wx, 0.0f) * 0.5f), wy);
  const float ir = 1.0f / fmaxf(rm, 1e-30f);
  float4 a4 = *(const float4*)(a2 + tid * 4);
  float4 b4 = *(const float4*)(b2 + tid * 4);
  float4 orr, oii;
  {
    float zx = r4.x - mx, zy = i4.x - my;
    orr.x = a4.x * ((zx * sre + zy * sim) * ir) + b4.x;
    oii.x = a4.x * ((zy * sre - zx * sim) * ir);
  }
  {
    float zx = r4.y - mx, zy = i4.y - my;
    orr.y = a4.y * ((zx * sre + zy * sim) * ir) + b4.y;
    oii.y = a4.y * ((zy * sre - zx * sim) * ir);
  }
  {
    float zx = r4.z - mx, zy = i4.z - my;
    orr.z = a4.z * ((zx * sre + zy * sim) * ir) + b4.z;
    oii.z = a4.z * ((zy * sre - zx * sim) * ir);
  }
  {
    float zx = r4.w - mx, zy = i4.w - my;
    orr.w = a4.w * ((zx * sre + zy * sim) * ir) + b4.w;
    oii.w = a4.w * ((zy * sre - zx * sim) * ir);
  }
  *(float4*)(outr + row * 1024 + tid * 4) = orr;
  *(float4*)(outi + row * 1024 + tid * 4) = oii;
}

extern "C" void kernel_launch(void* const* d_in, const int* in_sizes, int n_in,
                              void* d_out, int out_size, void* d_ws, size_t ws_size,
                              hipStream_t stream) {
  const float* X[6];
  for (int i = 0; i < 6; ++i) X[i] = (const float*)d_in[i];
  const float* W[6];
  const float* bia[6];
  for (int i = 0; i < 6; ++i) {
    W[i] = (const float*)d_in[6 + 2 * i];
    bia[i] = (const float*)d_in[7 + 2 * i];
  }
  const float* a2 = (const float*)d_in[18];
  const float* b2 = (const float*)d_in[19];

  char* ws = (char*)d_ws;
  char* qr = ws;
  char* qi = ws + 64 * MB;
  char* ki = ws + 128 * MB;
  char* krT = ws + 192 * MB;
  char* vrT = ws + 256 * MB;
  char* viT = ws + 320 * MB;
  char* Wsp[6];
  for (int i = 0; i < 6; ++i) Wsp[i] = ws + 384 * MB + (long)i * 4 * MB;

  char* dob = (char*)d_out;
  char* Xsp = dob;                       // [0, 64MB)
  float* Sf = (float*)dob;               // scores f32 (after Xsp dead)
  char* attn = dob + 64 * MB;            // attn split
  float* outr = (float*)ws;              // over qr_sp
  float* outi = (float*)(ws + 64 * MB);  // over qi_sp

  dim3 blk(256), gblk(512);
  dim3 proj_g(4, 64, 1), bat_g(4, 4, 16);

  // W splits
  for (int i = 0; i < 6; ++i)
    split_pass<<<dim3(512), blk, 0, stream>>>(W[i], Wsp[i], 131072L);

  // qr/qi/ki: X split -> gemm with direct-SP epilogue (EPI 2)
  split_pass<<<dim3(8192), blk, 0, stream>>>(X[0], Xsp, 2097152L);
  gemm_sp<2><<<proj_g, gblk, 0, stream>>>(Xsp, Wsp[0], nullptr, nullptr, 1, bia[0], nullptr, qr, 1.0f, 0, 0, 0);
  split_pass<<<dim3(8192), blk, 0, stream>>>(X[1], Xsp, 2097152L);
  gemm_sp<2><<<proj_g, gblk, 0, stream>>>(Xsp, Wsp[1], nullptr, nullptr, 1, bia[1], nullptr, qi, 1.0f, 0, 0, 0);
  split_pass<<<dim3(8192), blk, 0, stream>>>(X[3], Xsp, 2097152L);
  gemm_sp<2><<<proj_g, gblk, 0, stream>>>(Xsp, Wsp[3], nullptr, nullptr, 1, bia[3], nullptr, ki, 1.0f, 0, 0, 0);
  // krT / vrT / viT (transposed split epilogue)
  split_pass<<<dim3(8192), blk, 0, stream>>>(X[2], Xsp, 2097152L);
  gemm_sp<1><<<proj_g, gblk, 0, stream>>>(Xsp, Wsp[2], nullptr, nullptr, 1, bia[2], nullptr, krT, 1.0f, 0, 0, 0);
  split_pass<<<dim3(8192), blk, 0, stream>>>(X[4], Xsp, 2097152L);
  gemm_sp<1><<<proj_g, gblk, 0, stream>>>(Xsp, Wsp[4], nullptr, nullptr, 1, bia[4], nullptr, vrT, 1.0f, 0, 0, 0);
  split_pass<<<dim3(8192), blk, 0, stream>>>(X[5], Xsp, 2097152L);
  gemm_sp<1><<<proj_g, gblk, 0, stream>>>(Xsp, Wsp[5], nullptr, nullptr, 1, bia[5], nullptr, viT, 1.0f, 0, 0, 0);

  // scores = 0.125*(qr @ krT^T + qi @ ki^T), fused K=2048
  gemm_sp<0><<<bat_g, gblk, 0, stream>>>(qr, krT, qi, ki, 2, nullptr, Sf, nullptr, 0.125f,
                                         4 * MB, 4 * MB, 1048576L);
  // softmax + split
  softmax_split<<<dim3(16384), dim3(128), 0, stream>>>(Sf, attn);
  // out = attn @ v
  gemm_sp<0><<<bat_g, gblk, 0, stream>>>(attn, vrT, nullptr, nullptr, 1, nullptr, outr, nullptr, 1.0f,
                                         4 * MB, 4 * MB, 1048576L);
  gemm_sp<0><<<bat_g, gblk, 0, stream>>>(attn, viT, nullptr, nullptr, 1, nullptr, outi, nullptr, 1.0f,
                                         4 * MB, 4 * MB, 1048576L);
  // complex layernorm ws -> d_out
  complex_ln<<<dim3(16384), blk, 0, stream>>>(outr, outi, (float*)d_out,
                                              (float*)(dob + 64 * MB), a2, b2);
}